// Round 12
// baseline (468.574 us; speedup 1.0000x reference)
//
#include <hip/hip_runtime.h>
#include <hip/hip_bf16.h>

// Round 12: shuffle-free softmax in head. Phase1: gather+MFMA -> raw logits to
// swizzled LDS [128][64]. Phase2: one thread per edge-row reads 40 f32 from LDS,
// exp/sum/log (no max-sub: logits ~O(10), f32-safe), NT row store. No __shfl.
//   S = x@W1[0:128,:]            -> S   [50000][256] f16
//   Y' = x@W1[128:256,:]+b1      -> Ypr [50000][256] f16 (mean overwrites in-place)
//   bucket: pos=atomicAdd(cnt[d]); pad[d*128+pos]=(ushort)src
//   mean_d = avg_i relu(S[pad[d][i]]+Y'[d])   (wave per node, no LDS/barriers)
//   h = relu(mean@W2+b2); [P|Q'(+b3)] = h@W3cat -> PQ (aliases dead S)
//   z = relu(P[src]+Q'[dst]) (packed f16); logits=z@W4+b4 -> LDS; log_softmax -> out
// ws layout identical to round 11 (~64.5 MB).

typedef _Float16 f16x8 __attribute__((ext_vector_type(8)));
typedef _Float16 f16x4 __attribute__((ext_vector_type(4)));
typedef float f32x4 __attribute__((ext_vector_type(4)));

#define N_NODES 50000
#define N_EDGES 800000

__device__ __forceinline__ unsigned short f2h(float f) {
  _Float16 h = (_Float16)f;  // v_cvt_f16_f32 (RNE)
  return __builtin_bit_cast(unsigned short, h);
}
// int64-vs-int32 edge_index probe (values < 2^31 -> high words zero)
__device__ __forceinline__ int probe64(const int* ei) {
  return (ei[1] == 0 && ei[3] == 0 && ei[5] == 0 && ei[7] == 0) ? 1 : 0;
}
__device__ __forceinline__ int ld_src(const int* ei, int m64, int e) {
  return m64 ? ei[2 * e] : ei[e];
}
__device__ __forceinline__ int ld_dst(const int* ei, int m64, int e) {
  return m64 ? ei[2 * N_EDGES + 2 * e] : ei[N_EDGES + e];
}

// Fused: blocks [0,537) pack weight fragments; blocks [537,3662) count+bucket-scatter.
__global__ void k_prep_scatter(const float* __restrict__ W1, const float* __restrict__ W2,
                               const float* __restrict__ W3, const float* __restrict__ W4,
                               const float* __restrict__ b4,
                               unsigned short* __restrict__ w1f, unsigned short* __restrict__ w2f,
                               unsigned short* __restrict__ w3f, unsigned short* __restrict__ w4f,
                               float* __restrict__ b4p, const int* __restrict__ ei,
                               int* __restrict__ cnt, unsigned short* __restrict__ pad) {
  const int t = threadIdx.x;
  if (blockIdx.x >= 537) {
    int e = (blockIdx.x - 537) * 256 + t;
    int m64 = probe64(ei);
    int s = ld_src(ei, m64, e), d = ld_dst(ei, m64, e);
    int pos = atomicAdd(&cnt[d], 1);
    pad[(d << 7) + pos] = (unsigned short)s;
    return;
  }
  int gid = blockIdx.x * 256 + t;
  if (gid < 65536) {  // w1f: Bcat1[128][512], ct32 ks4
    int i = gid & 7, lane = (gid >> 3) & 63, ks = (gid >> 9) & 3, ct = gid >> 11;
    int k = ks * 32 + (lane >> 4) * 8 + i;
    int c = ct * 16 + (lane & 15);
    float v = (c < 256) ? W1[k * 256 + c] : W1[(128 + k) * 256 + (c - 256)];
    w1f[gid] = f2h(v);
  } else if (gid < 98304) {  // w2f: W2[256][128], ct8 ks8
    int f = gid - 65536;
    int i = f & 7, lane = (f >> 3) & 63, ks = (f >> 9) & 7, ct = f >> 12;
    int k = ks * 32 + (lane >> 4) * 8 + i;
    int c = ct * 16 + (lane & 15);
    w2f[f] = f2h(W2[k * 128 + c]);
  } else if (gid < 131072) {  // w3f: Bcat3[128][256], ct16 ks4
    int f = gid - 98304;
    int i = f & 7, lane = (f >> 3) & 63, ks = (f >> 9) & 3, ct = f >> 11;
    int k = ks * 32 + (lane >> 4) * 8 + i;
    int c = ct * 16 + (lane & 15);
    float v = (c < 128) ? W3[k * 128 + c] : W3[(128 + k) * 128 + (c - 128)];
    w3f[f] = f2h(v);
  } else if (gid < 137216) {  // w4f: W4[128][40->48], ct3 ks4
    int f = gid - 131072;
    int i = f & 7, lane = (f >> 3) & 63, ks = (f >> 9) & 3, ct = f >> 11;
    int k = ks * 32 + (lane >> 4) * 8 + i;
    int c = ct * 16 + (lane & 15);
    w4f[f] = (c < 40) ? f2h(W4[k * 40 + c]) : (unsigned short)0;
  } else if (gid < 137264) {
    int c = gid - 137216;
    b4p[c] = (c < 40) ? b4[c] : 0.f;
  }
}

// SY GEMM: [S|Y'] = x @ [W1top | W1bot], +b1 on Y' cols. 64-row tiles, 8 waves.
__global__ __launch_bounds__(512, 2) void k_sy(const float* __restrict__ x,
                                               const unsigned short* __restrict__ w1f,
                                               const float* __restrict__ b1,
                                               unsigned short* __restrict__ S,
                                               unsigned short* __restrict__ Ypr) {
  __shared__ __attribute__((aligned(16))) short A[64 * 128];  // 16 KB swizzled (256B rows)
  const int t = threadIdx.x;
  const int nb = blockIdx.x * 64;
  const int nv = min(64, N_NODES - nb);
  const int w = t >> 6, l = t & 63, lr = l & 15, lh = l >> 4;

  f16x8 B[4][4];
#pragma unroll
  for (int ci = 0; ci < 4; ++ci)
#pragma unroll
    for (int ks = 0; ks < 4; ++ks)
      B[ci][ks] = *(const f16x8*)(w1f + (((w * 4 + ci) * 4 + ks) * 64 + l) * 8);

#pragma unroll
  for (int j = 0; j < 2; ++j) {
    int c = t + 512 * j;
    int row = c >> 4, ck = c & 15;
    int rr = (row < nv) ? row : 0;
    const float* gp = x + (long)(nb + rr) * 128 + ck * 8;
    float4 v0 = *(const float4*)gp;
    float4 v1 = *(const float4*)(gp + 4);
    f16x8 o;
    o[0] = (_Float16)v0.x; o[1] = (_Float16)v0.y;
    o[2] = (_Float16)v0.z; o[3] = (_Float16)v0.w;
    o[4] = (_Float16)v1.x; o[5] = (_Float16)v1.y;
    o[6] = (_Float16)v1.z; o[7] = (_Float16)v1.w;
    int off = (row << 8) + (ck << 4);
    off ^= (row & 7) << 4;
    *(f16x8*)((char*)A + off) = o;
  }
  __syncthreads();

#pragma unroll
  for (int rt = 0; rt < 4; ++rt) {
    f32x4 acc[4] = {};
#pragma unroll
    for (int ks = 0; ks < 4; ++ks) {
      int row = rt * 16 + lr;
      int off = (row << 8) + (ks << 6) + (lh << 4);
      off ^= (row & 7) << 4;
      f16x8 a = *(const f16x8*)((const char*)A + off);
#pragma unroll
      for (int ci = 0; ci < 4; ++ci)
        acc[ci] = __builtin_amdgcn_mfma_f32_16x16x32_f16(a, B[ci][ks], acc[ci], 0, 0, 0);
    }
#pragma unroll
    for (int ci = 0; ci < 4; ++ci) {
      int col = (w * 4 + ci) * 16 + lr;
#pragma unroll
      for (int r = 0; r < 4; ++r) {
        int row = rt * 16 + lh * 4 + r;
        if (row < nv) {
          if (col < 256) {
            S[(long)(nb + row) * 256 + col] = f2h(acc[ci][r]);
          } else {
            Ypr[(long)(nb + row) * 256 + (col - 256)] = f2h(acc[ci][r] + b1[col - 256]);
          }
        }
      }
    }
  }
}

// Mean of relu(S[s]+Y'[d]) over node d's bucket; one wave per node, lane owns 4 dims.
__global__ __launch_bounds__(512) void k_edge_agg(const unsigned short* __restrict__ S,
                                                  unsigned short* __restrict__ Ypr,
                                                  const int* __restrict__ cnt,
                                                  const unsigned short* __restrict__ pad) {
  const int t = threadIdx.x, w = t >> 6, l = t & 63;
  const int d = blockIdx.x * 8 + w;
  const int n = cnt[d];
  const unsigned short* lp = pad + (d << 7);
  unsigned short* Yp = Ypr + (long)d * 256 + l * 4;
  const f16x4 y = *(const f16x4*)Yp;
  float a0 = 0.f, a1 = 0.f, a2 = 0.f, a3 = 0.f;
  int pos = 0;
  for (; pos + 8 <= n; pos += 8) {
    f16x4 u[8];
#pragma unroll
    for (int j = 0; j < 8; ++j) {
      int s = (int)lp[pos + j];
      u[j] = *(const f16x4*)(S + (long)s * 256 + l * 4);
    }
#pragma unroll
    for (int j = 0; j < 8; ++j) {
      f16x4 z = u[j] + y;                              // v_pk_add_f16 x2
      z = __builtin_elementwise_max(z, f16x4{});       // v_pk_max_f16 x2
      a0 += (float)z[0]; a1 += (float)z[1];
      a2 += (float)z[2]; a3 += (float)z[3];
    }
  }
  for (; pos < n; ++pos) {
    int s = (int)lp[pos];
    f16x4 u = *(const f16x4*)(S + (long)s * 256 + l * 4);
    f16x4 z = u + y;
    z = __builtin_elementwise_max(z, f16x4{});
    a0 += (float)z[0]; a1 += (float)z[1];
    a2 += (float)z[2]; a3 += (float)z[3];
  }
  float inv = 1.0f / fmaxf((float)n, 1.0f);
  f16x4 o;
  o[0] = (_Float16)(a0 * inv); o[1] = (_Float16)(a1 * inv);
  o[2] = (_Float16)(a2 * inv); o[3] = (_Float16)(a3 * inv);
  *(f16x4*)Yp = o;  // mean overwrites Y' (only this wave touches row d)
}

// h = relu(mean@W2+b2); [P|Q'(+b3)] = h@W3cat -> PQ (aliases dead S). 64 nodes/block.
__global__ __launch_bounds__(256, 2) void k_pq(const unsigned short* __restrict__ Ypr,
                                               unsigned short* __restrict__ PQ,
                                               const unsigned short* __restrict__ w2f,
                                               const float* __restrict__ b2,
                                               const unsigned short* __restrict__ w3f,
                                               const float* __restrict__ b3) {
  __shared__ __attribute__((aligned(16))) short M[64 * 256];  // 32 KB (512B rows, swizzled)
  __shared__ __attribute__((aligned(16))) short H[64 * 128];  // 16 KB (256B rows, swizzled)
  const int t = threadIdx.x;
  const int nb = blockIdx.x * 64;
  const int nv = min(64, N_NODES - nb);
  const int w = t >> 6, l = t & 63, lr = l & 15, lh = l >> 4;

  f16x8 B2[2][8];
#pragma unroll
  for (int ci = 0; ci < 2; ++ci)
#pragma unroll
    for (int ks = 0; ks < 8; ++ks)
      B2[ci][ks] = *(const f16x8*)(w2f + (((w * 2 + ci) * 8 + ks) * 64 + l) * 8);

#pragma unroll
  for (int j = 0; j < 8; ++j) {
    int c = t + 256 * j;
    int row = c >> 5, ck = c & 31;
    int rr = (row < nv) ? row : 0;
    int4 v = *(const int4*)(Ypr + (long)(nb + rr) * 256 + ck * 8);
    int off = (row << 9) + (ck << 4);
    off ^= (row & 7) << 4;
    *(int4*)((char*)M + off) = v;
  }
  __syncthreads();

#pragma unroll
  for (int rt = 0; rt < 4; ++rt) {
    f32x4 acc[2] = {};
#pragma unroll
    for (int ks = 0; ks < 8; ++ks) {
      int row = rt * 16 + lr;
      int off = (row << 9) + (ks << 6) + (lh << 4);
      off ^= (row & 7) << 4;
      f16x8 a = *(const f16x8*)((const char*)M + off);
      acc[0] = __builtin_amdgcn_mfma_f32_16x16x32_f16(a, B2[0][ks], acc[0], 0, 0, 0);
      acc[1] = __builtin_amdgcn_mfma_f32_16x16x32_f16(a, B2[1][ks], acc[1], 0, 0, 0);
    }
#pragma unroll
    for (int ci = 0; ci < 2; ++ci) {
      int col = (w * 2 + ci) * 16 + lr;
      float bb = b2[col];
#pragma unroll
      for (int r = 0; r < 4; ++r) {
        int row = rt * 16 + lh * 4 + r;
        int off = (row << 8) + (col << 1);
        off ^= (row & 7) << 4;
        *(short*)((char*)H + off) = (short)f2h(fmaxf(acc[ci][r] + bb, 0.f));
      }
    }
  }
  __syncthreads();

  f16x8 B3[4][4];
#pragma unroll
  for (int ci = 0; ci < 4; ++ci)
#pragma unroll
    for (int ks = 0; ks < 4; ++ks)
      B3[ci][ks] = *(const f16x8*)(w3f + (((w * 4 + ci) * 4 + ks) * 64 + l) * 8);

#pragma unroll
  for (int rt = 0; rt < 4; ++rt) {
    f32x4 acc[4] = {};
#pragma unroll
    for (int ks = 0; ks < 4; ++ks) {
      int row = rt * 16 + lr;
      int off = (row << 8) + (ks << 6) + (lh << 4);
      off ^= (row & 7) << 4;
      f16x8 a = *(const f16x8*)((const char*)H + off);
#pragma unroll
      for (int ci = 0; ci < 4; ++ci)
        acc[ci] = __builtin_amdgcn_mfma_f32_16x16x32_f16(a, B3[ci][ks], acc[ci], 0, 0, 0);
    }
#pragma unroll
    for (int ci = 0; ci < 4; ++ci) {
      int col = (w * 4 + ci) * 16 + lr;
      float bb = (col >= 128) ? b3[col - 128] : 0.f;
#pragma unroll
      for (int r = 0; r < 4; ++r) {
        int row = rt * 16 + lh * 4 + r;
        if (row < nv) PQ[(long)(nb + row) * 256 + col] = f2h(acc[ci][r] + bb);
      }
    }
  }
}

// Head: phase1 = 2-chain gather + packed-f16 z + MFMA -> biased logits into
// swizzled LDS [128 rows][64 cols]; phase2 = 1 thread/row, shuffle-free
// log-softmax (no max-sub; logits O(10), f32 exp safe), NT row stores.
__global__ __launch_bounds__(256) void k_head(const unsigned short* __restrict__ PQ,
                                              const int* __restrict__ ei,
                                              const unsigned short* __restrict__ w4f,
                                              const float* __restrict__ b4p,
                                              float* __restrict__ out) {
  __shared__ __attribute__((aligned(16))) float lg[128 * 64];  // 32 KB, 16B-chunk swizzle
  const int t = threadIdx.x, w = t >> 6, l = t & 63, lr = l & 15, lh = l >> 4;
  const int m64 = probe64(ei);
  const int eb = blockIdx.x * 128 + w * 32;
  const int elA = eb + lr;
  const int elB = eb + 16 + lr;
  const int snA = ld_src(ei, m64, elA), dnA = ld_dst(ei, m64, elA);
  const int snB = ld_src(ei, m64, elB), dnB = ld_dst(ei, m64, elB);
  const unsigned short* PpA = PQ + (long)snA * 256;
  const unsigned short* QpA = PQ + (long)dnA * 256 + 128;
  const unsigned short* PpB = PQ + (long)snB * 256;
  const unsigned short* QpB = PQ + (long)dnB * 256 + 128;

  f16x8 B4[3][4];
#pragma unroll
  for (int ci = 0; ci < 3; ++ci)
#pragma unroll
    for (int ks = 0; ks < 4; ++ks)
      B4[ci][ks] = *(const f16x8*)(w4f + ((ci * 4 + ks) * 64 + l) * 8);

  f32x4 accA[3] = {};
  f32x4 accB[3] = {};
#pragma unroll
  for (int ks = 0; ks < 4; ++ks) {
    f16x8 pA = *(const f16x8*)(PpA + ks * 32 + lh * 8);
    f16x8 qA = *(const f16x8*)(QpA + ks * 32 + lh * 8);
    f16x8 pB = *(const f16x8*)(PpB + ks * 32 + lh * 8);
    f16x8 qB = *(const f16x8*)(QpB + ks * 32 + lh * 8);
    f16x8 zA = pA + qA;                              // 4x v_pk_add_f16
    zA = __builtin_elementwise_max(zA, f16x8{});     // 4x v_pk_max_f16
    f16x8 zB = pB + qB;
    zB = __builtin_elementwise_max(zB, f16x8{});
#pragma unroll
    for (int ci = 0; ci < 3; ++ci) {
      accA[ci] = __builtin_amdgcn_mfma_f32_16x16x32_f16(zA, B4[ci][ks], accA[ci], 0, 0, 0);
      accB[ci] = __builtin_amdgcn_mfma_f32_16x16x32_f16(zB, B4[ci][ks], accB[ci], 0, 0, 0);
    }
  }

  // biased logits -> LDS, swizzled at 16B granularity: word addr =
  // row*64 + ((chunk ^ (row&15))<<2) + off, chunk=word>>2.
#pragma unroll
  for (int es = 0; es < 2; ++es) {
    f32x4* ac = es ? accB : accA;
#pragma unroll
    for (int ci = 0; ci < 3; ++ci) {
      int word = ci * 16 + lr;
      int chunk = word >> 2, off = word & 3;
      float bb = b4p[word];
#pragma unroll
      for (int r = 0; r < 4; ++r) {
        int row = w * 32 + es * 16 + lh * 4 + r;
        lg[row * 64 + ((chunk ^ (row & 15)) << 2) + off] = ac[ci][r] + bb;
      }
    }
  }
  __syncthreads();
  if (t >= 128) return;

  // phase 2: one thread per row; 10x ds_read_b128, exp-sum, log, NT stores.
  float v[40];
  float s = 0.f;
#pragma unroll
  for (int c = 0; c < 10; ++c) {
    f32x4 q = *(const f32x4*)&lg[t * 64 + ((c ^ (t & 15)) << 2)];
    v[c * 4 + 0] = q[0]; v[c * 4 + 1] = q[1];
    v[c * 4 + 2] = q[2]; v[c * 4 + 3] = q[3];
  }
#pragma unroll
  for (int i = 0; i < 40; ++i) s += __expf(v[i]);
  float lse = __logf(s);
  float* op = out + ((long)blockIdx.x * 128 + t) * 40;
#pragma unroll
  for (int c = 0; c < 10; ++c) {
    f32x4 o;
    o[0] = v[c * 4 + 0] - lse; o[1] = v[c * 4 + 1] - lse;
    o[2] = v[c * 4 + 2] - lse; o[3] = v[c * 4 + 3] - lse;
    __builtin_nontemporal_store(o, (f32x4*)(op + c * 4));
  }
}

extern "C" void kernel_launch(void* const* d_in, const int* in_sizes, int n_in,
                              void* d_out, int out_size, void* d_ws, size_t ws_size,
                              hipStream_t stream) {
  const float* x = (const float*)d_in[0];
  const int* ei = (const int*)d_in[1];
  const float* W1 = (const float*)d_in[2];
  const float* b1 = (const float*)d_in[3];
  const float* W2 = (const float*)d_in[4];
  const float* b2 = (const float*)d_in[5];
  const float* W3 = (const float*)d_in[6];
  const float* b3 = (const float*)d_in[7];
  const float* W4 = (const float*)d_in[8];
  const float* b4 = (const float*)d_in[9];
  char* ws = (char*)d_ws;
  int* cnt = (int*)(ws + 0);
  unsigned short* pad = (unsigned short*)(ws + 200064);
  unsigned short* S = (unsigned short*)(ws + 13000192);  // PQ aliases S (dead after agg)
  unsigned short* Ypr = (unsigned short*)(ws + 38600192);
  unsigned short* w1f = (unsigned short*)(ws + 64200192);
  unsigned short* w2f = (unsigned short*)(ws + 64331264);
  unsigned short* w3f = (unsigned short*)(ws + 64396800);
  unsigned short* w4f = (unsigned short*)(ws + 64462336);
  float* b4p = (float*)(ws + 64474624);
  float* out = (float*)d_out;

  (void)hipMemsetAsync(ws, 0, 200064, stream);  // cnt
  k_prep_scatter<<<3662, 256, 0, stream>>>(W1, W2, W3, W4, b4, w1f, w2f, w3f, w4f, b4p,
                                           ei, cnt, pad);
  k_sy<<<782, 512, 0, stream>>>(x, w1f, b1, S, Ypr);
  k_edge_agg<<<6250, 512, 0, stream>>>(S, Ypr, cnt, pad);
  k_pq<<<782, 256, 0, stream>>>(Ypr, S, w2f, b2, w3f, b3);
  k_head<<<6250, 256, 0, stream>>>(S, ei, w4f, b4p, out);
}

// Round 13
// 281.210 us; speedup vs baseline: 1.6663x; 1.6663x over previous
//
#include <hip/hip_runtime.h>
#include <hip/hip_bf16.h>

// Round 13: round-12 shuffle-free softmax, but PLAIN row stores (L2 merges the
// contiguous-per-block 20 KB; round-12's NT scatter caused 444MB write-amp).
//   S = x@W1[0:128,:]            -> S   [50000][256] f16
//   Y' = x@W1[128:256,:]+b1      -> Ypr [50000][256] f16 (mean overwrites in-place)
//   bucket: pos=atomicAdd(cnt[d]); pad[d*128+pos]=(ushort)src
//   mean_d = avg_i relu(S[pad[d][i]]+Y'[d])   (wave per node, no LDS/barriers)
//   h = relu(mean@W2+b2); [P|Q'(+b3)] = h@W3cat -> PQ (aliases dead S)
//   z = relu(P[src]+Q'[dst]) (packed f16); logits=z@W4+b4 -> LDS; log_softmax -> out
// ws layout identical to round 11 (~64.5 MB).

typedef _Float16 f16x8 __attribute__((ext_vector_type(8)));
typedef _Float16 f16x4 __attribute__((ext_vector_type(4)));
typedef float f32x4 __attribute__((ext_vector_type(4)));

#define N_NODES 50000
#define N_EDGES 800000

__device__ __forceinline__ unsigned short f2h(float f) {
  _Float16 h = (_Float16)f;  // v_cvt_f16_f32 (RNE)
  return __builtin_bit_cast(unsigned short, h);
}
// int64-vs-int32 edge_index probe (values < 2^31 -> high words zero)
__device__ __forceinline__ int probe64(const int* ei) {
  return (ei[1] == 0 && ei[3] == 0 && ei[5] == 0 && ei[7] == 0) ? 1 : 0;
}
__device__ __forceinline__ int ld_src(const int* ei, int m64, int e) {
  return m64 ? ei[2 * e] : ei[e];
}
__device__ __forceinline__ int ld_dst(const int* ei, int m64, int e) {
  return m64 ? ei[2 * N_EDGES + 2 * e] : ei[N_EDGES + e];
}

// Fused: blocks [0,537) pack weight fragments; blocks [537,3662) count+bucket-scatter.
__global__ void k_prep_scatter(const float* __restrict__ W1, const float* __restrict__ W2,
                               const float* __restrict__ W3, const float* __restrict__ W4,
                               const float* __restrict__ b4,
                               unsigned short* __restrict__ w1f, unsigned short* __restrict__ w2f,
                               unsigned short* __restrict__ w3f, unsigned short* __restrict__ w4f,
                               float* __restrict__ b4p, const int* __restrict__ ei,
                               int* __restrict__ cnt, unsigned short* __restrict__ pad) {
  const int t = threadIdx.x;
  if (blockIdx.x >= 537) {
    int e = (blockIdx.x - 537) * 256 + t;
    int m64 = probe64(ei);
    int s = ld_src(ei, m64, e), d = ld_dst(ei, m64, e);
    int pos = atomicAdd(&cnt[d], 1);
    pad[(d << 7) + pos] = (unsigned short)s;
    return;
  }
  int gid = blockIdx.x * 256 + t;
  if (gid < 65536) {  // w1f: Bcat1[128][512], ct32 ks4
    int i = gid & 7, lane = (gid >> 3) & 63, ks = (gid >> 9) & 3, ct = gid >> 11;
    int k = ks * 32 + (lane >> 4) * 8 + i;
    int c = ct * 16 + (lane & 15);
    float v = (c < 256) ? W1[k * 256 + c] : W1[(128 + k) * 256 + (c - 256)];
    w1f[gid] = f2h(v);
  } else if (gid < 98304) {  // w2f: W2[256][128], ct8 ks8
    int f = gid - 65536;
    int i = f & 7, lane = (f >> 3) & 63, ks = (f >> 9) & 7, ct = f >> 12;
    int k = ks * 32 + (lane >> 4) * 8 + i;
    int c = ct * 16 + (lane & 15);
    w2f[f] = f2h(W2[k * 128 + c]);
  } else if (gid < 131072) {  // w3f: Bcat3[128][256], ct16 ks4
    int f = gid - 98304;
    int i = f & 7, lane = (f >> 3) & 63, ks = (f >> 9) & 3, ct = f >> 11;
    int k = ks * 32 + (lane >> 4) * 8 + i;
    int c = ct * 16 + (lane & 15);
    float v = (c < 128) ? W3[k * 128 + c] : W3[(128 + k) * 128 + (c - 128)];
    w3f[f] = f2h(v);
  } else if (gid < 137216) {  // w4f: W4[128][40->48], ct3 ks4
    int f = gid - 131072;
    int i = f & 7, lane = (f >> 3) & 63, ks = (f >> 9) & 3, ct = f >> 11;
    int k = ks * 32 + (lane >> 4) * 8 + i;
    int c = ct * 16 + (lane & 15);
    w4f[f] = (c < 40) ? f2h(W4[k * 40 + c]) : (unsigned short)0;
  } else if (gid < 137264) {
    int c = gid - 137216;
    b4p[c] = (c < 40) ? b4[c] : 0.f;
  }
}

// SY GEMM: [S|Y'] = x @ [W1top | W1bot], +b1 on Y' cols. 64-row tiles, 8 waves.
__global__ __launch_bounds__(512, 2) void k_sy(const float* __restrict__ x,
                                               const unsigned short* __restrict__ w1f,
                                               const float* __restrict__ b1,
                                               unsigned short* __restrict__ S,
                                               unsigned short* __restrict__ Ypr) {
  __shared__ __attribute__((aligned(16))) short A[64 * 128];  // 16 KB swizzled (256B rows)
  const int t = threadIdx.x;
  const int nb = blockIdx.x * 64;
  const int nv = min(64, N_NODES - nb);
  const int w = t >> 6, l = t & 63, lr = l & 15, lh = l >> 4;

  f16x8 B[4][4];
#pragma unroll
  for (int ci = 0; ci < 4; ++ci)
#pragma unroll
    for (int ks = 0; ks < 4; ++ks)
      B[ci][ks] = *(const f16x8*)(w1f + (((w * 4 + ci) * 4 + ks) * 64 + l) * 8);

#pragma unroll
  for (int j = 0; j < 2; ++j) {
    int c = t + 512 * j;
    int row = c >> 4, ck = c & 15;
    int rr = (row < nv) ? row : 0;
    const float* gp = x + (long)(nb + rr) * 128 + ck * 8;
    float4 v0 = *(const float4*)gp;
    float4 v1 = *(const float4*)(gp + 4);
    f16x8 o;
    o[0] = (_Float16)v0.x; o[1] = (_Float16)v0.y;
    o[2] = (_Float16)v0.z; o[3] = (_Float16)v0.w;
    o[4] = (_Float16)v1.x; o[5] = (_Float16)v1.y;
    o[6] = (_Float16)v1.z; o[7] = (_Float16)v1.w;
    int off = (row << 8) + (ck << 4);
    off ^= (row & 7) << 4;
    *(f16x8*)((char*)A + off) = o;
  }
  __syncthreads();

#pragma unroll
  for (int rt = 0; rt < 4; ++rt) {
    f32x4 acc[4] = {};
#pragma unroll
    for (int ks = 0; ks < 4; ++ks) {
      int row = rt * 16 + lr;
      int off = (row << 8) + (ks << 6) + (lh << 4);
      off ^= (row & 7) << 4;
      f16x8 a = *(const f16x8*)((const char*)A + off);
#pragma unroll
      for (int ci = 0; ci < 4; ++ci)
        acc[ci] = __builtin_amdgcn_mfma_f32_16x16x32_f16(a, B[ci][ks], acc[ci], 0, 0, 0);
    }
#pragma unroll
    for (int ci = 0; ci < 4; ++ci) {
      int col = (w * 4 + ci) * 16 + lr;
#pragma unroll
      for (int r = 0; r < 4; ++r) {
        int row = rt * 16 + lh * 4 + r;
        if (row < nv) {
          if (col < 256) {
            S[(long)(nb + row) * 256 + col] = f2h(acc[ci][r]);
          } else {
            Ypr[(long)(nb + row) * 256 + (col - 256)] = f2h(acc[ci][r] + b1[col - 256]);
          }
        }
      }
    }
  }
}

// Mean of relu(S[s]+Y'[d]) over node d's bucket; one wave per node, lane owns 4 dims.
__global__ __launch_bounds__(512) void k_edge_agg(const unsigned short* __restrict__ S,
                                                  unsigned short* __restrict__ Ypr,
                                                  const int* __restrict__ cnt,
                                                  const unsigned short* __restrict__ pad) {
  const int t = threadIdx.x, w = t >> 6, l = t & 63;
  const int d = blockIdx.x * 8 + w;
  const int n = cnt[d];
  const unsigned short* lp = pad + (d << 7);
  unsigned short* Yp = Ypr + (long)d * 256 + l * 4;
  const f16x4 y = *(const f16x4*)Yp;
  float a0 = 0.f, a1 = 0.f, a2 = 0.f, a3 = 0.f;
  int pos = 0;
  for (; pos + 8 <= n; pos += 8) {
    f16x4 u[8];
#pragma unroll
    for (int j = 0; j < 8; ++j) {
      int s = (int)lp[pos + j];
      u[j] = *(const f16x4*)(S + (long)s * 256 + l * 4);
    }
#pragma unroll
    for (int j = 0; j < 8; ++j) {
      f16x4 z = u[j] + y;                              // v_pk_add_f16 x2
      z = __builtin_elementwise_max(z, f16x4{});       // v_pk_max_f16 x2
      a0 += (float)z[0]; a1 += (float)z[1];
      a2 += (float)z[2]; a3 += (float)z[3];
    }
  }
  for (; pos < n; ++pos) {
    int s = (int)lp[pos];
    f16x4 u = *(const f16x4*)(S + (long)s * 256 + l * 4);
    f16x4 z = u + y;
    z = __builtin_elementwise_max(z, f16x4{});
    a0 += (float)z[0]; a1 += (float)z[1];
    a2 += (float)z[2]; a3 += (float)z[3];
  }
  float inv = 1.0f / fmaxf((float)n, 1.0f);
  f16x4 o;
  o[0] = (_Float16)(a0 * inv); o[1] = (_Float16)(a1 * inv);
  o[2] = (_Float16)(a2 * inv); o[3] = (_Float16)(a3 * inv);
  *(f16x4*)Yp = o;  // mean overwrites Y' (only this wave touches row d)
}

// h = relu(mean@W2+b2); [P|Q'(+b3)] = h@W3cat -> PQ (aliases dead S). 64 nodes/block.
__global__ __launch_bounds__(256, 2) void k_pq(const unsigned short* __restrict__ Ypr,
                                               unsigned short* __restrict__ PQ,
                                               const unsigned short* __restrict__ w2f,
                                               const float* __restrict__ b2,
                                               const unsigned short* __restrict__ w3f,
                                               const float* __restrict__ b3) {
  __shared__ __attribute__((aligned(16))) short M[64 * 256];  // 32 KB (512B rows, swizzled)
  __shared__ __attribute__((aligned(16))) short H[64 * 128];  // 16 KB (256B rows, swizzled)
  const int t = threadIdx.x;
  const int nb = blockIdx.x * 64;
  const int nv = min(64, N_NODES - nb);
  const int w = t >> 6, l = t & 63, lr = l & 15, lh = l >> 4;

  f16x8 B2[2][8];
#pragma unroll
  for (int ci = 0; ci < 2; ++ci)
#pragma unroll
    for (int ks = 0; ks < 8; ++ks)
      B2[ci][ks] = *(const f16x8*)(w2f + (((w * 2 + ci) * 8 + ks) * 64 + l) * 8);

#pragma unroll
  for (int j = 0; j < 8; ++j) {
    int c = t + 256 * j;
    int row = c >> 5, ck = c & 31;
    int rr = (row < nv) ? row : 0;
    int4 v = *(const int4*)(Ypr + (long)(nb + rr) * 256 + ck * 8);
    int off = (row << 9) + (ck << 4);
    off ^= (row & 7) << 4;
    *(int4*)((char*)M + off) = v;
  }
  __syncthreads();

#pragma unroll
  for (int rt = 0; rt < 4; ++rt) {
    f32x4 acc[2] = {};
#pragma unroll
    for (int ks = 0; ks < 8; ++ks) {
      int row = rt * 16 + lr;
      int off = (row << 9) + (ks << 6) + (lh << 4);
      off ^= (row & 7) << 4;
      f16x8 a = *(const f16x8*)((const char*)M + off);
      acc[0] = __builtin_amdgcn_mfma_f32_16x16x32_f16(a, B2[0][ks], acc[0], 0, 0, 0);
      acc[1] = __builtin_amdgcn_mfma_f32_16x16x32_f16(a, B2[1][ks], acc[1], 0, 0, 0);
    }
#pragma unroll
    for (int ci = 0; ci < 2; ++ci) {
      int col = (w * 2 + ci) * 16 + lr;
      float bb = b2[col];
#pragma unroll
      for (int r = 0; r < 4; ++r) {
        int row = rt * 16 + lh * 4 + r;
        int off = (row << 8) + (col << 1);
        off ^= (row & 7) << 4;
        *(short*)((char*)H + off) = (short)f2h(fmaxf(acc[ci][r] + bb, 0.f));
      }
    }
  }
  __syncthreads();

  f16x8 B3[4][4];
#pragma unroll
  for (int ci = 0; ci < 4; ++ci)
#pragma unroll
    for (int ks = 0; ks < 4; ++ks)
      B3[ci][ks] = *(const f16x8*)(w3f + (((w * 4 + ci) * 4 + ks) * 64 + l) * 8);

#pragma unroll
  for (int rt = 0; rt < 4; ++rt) {
    f32x4 acc[4] = {};
#pragma unroll
    for (int ks = 0; ks < 4; ++ks) {
      int row = rt * 16 + lr;
      int off = (row << 8) + (ks << 6) + (lh << 4);
      off ^= (row & 7) << 4;
      f16x8 a = *(const f16x8*)((const char*)H + off);
#pragma unroll
      for (int ci = 0; ci < 4; ++ci)
        acc[ci] = __builtin_amdgcn_mfma_f32_16x16x32_f16(a, B3[ci][ks], acc[ci], 0, 0, 0);
    }
#pragma unroll
    for (int ci = 0; ci < 4; ++ci) {
      int col = (w * 4 + ci) * 16 + lr;
      float bb = (col >= 128) ? b3[col - 128] : 0.f;
#pragma unroll
      for (int r = 0; r < 4; ++r) {
        int row = rt * 16 + lh * 4 + r;
        if (row < nv) PQ[(long)(nb + row) * 256 + col] = f2h(acc[ci][r] + bb);
      }
    }
  }
}

// Head: phase1 = 2-chain gather + packed-f16 z + MFMA -> biased logits into
// swizzled LDS [128 rows][64 cols]; phase2 = 1 thread/row, shuffle-free
// log-softmax (no max-sub; logits O(10), f32 exp safe), PLAIN row stores
// (contiguous per block; L2 merges into full lines).
__global__ __launch_bounds__(256) void k_head(const unsigned short* __restrict__ PQ,
                                              const int* __restrict__ ei,
                                              const unsigned short* __restrict__ w4f,
                                              const float* __restrict__ b4p,
                                              float* __restrict__ out) {
  __shared__ __attribute__((aligned(16))) float lg[128 * 64];  // 32 KB, 16B-chunk swizzle
  const int t = threadIdx.x, w = t >> 6, l = t & 63, lr = l & 15, lh = l >> 4;
  const int m64 = probe64(ei);
  const int eb = blockIdx.x * 128 + w * 32;
  const int elA = eb + lr;
  const int elB = eb + 16 + lr;
  const int snA = ld_src(ei, m64, elA), dnA = ld_dst(ei, m64, elA);
  const int snB = ld_src(ei, m64, elB), dnB = ld_dst(ei, m64, elB);
  const unsigned short* PpA = PQ + (long)snA * 256;
  const unsigned short* QpA = PQ + (long)dnA * 256 + 128;
  const unsigned short* PpB = PQ + (long)snB * 256;
  const unsigned short* QpB = PQ + (long)dnB * 256 + 128;

  f16x8 B4[3][4];
#pragma unroll
  for (int ci = 0; ci < 3; ++ci)
#pragma unroll
    for (int ks = 0; ks < 4; ++ks)
      B4[ci][ks] = *(const f16x8*)(w4f + ((ci * 4 + ks) * 64 + l) * 8);

  f32x4 accA[3] = {};
  f32x4 accB[3] = {};
#pragma unroll
  for (int ks = 0; ks < 4; ++ks) {
    f16x8 pA = *(const f16x8*)(PpA + ks * 32 + lh * 8);
    f16x8 qA = *(const f16x8*)(QpA + ks * 32 + lh * 8);
    f16x8 pB = *(const f16x8*)(PpB + ks * 32 + lh * 8);
    f16x8 qB = *(const f16x8*)(QpB + ks * 32 + lh * 8);
    f16x8 zA = pA + qA;                              // 4x v_pk_add_f16
    zA = __builtin_elementwise_max(zA, f16x8{});     // 4x v_pk_max_f16
    f16x8 zB = pB + qB;
    zB = __builtin_elementwise_max(zB, f16x8{});
#pragma unroll
    for (int ci = 0; ci < 3; ++ci) {
      accA[ci] = __builtin_amdgcn_mfma_f32_16x16x32_f16(zA, B4[ci][ks], accA[ci], 0, 0, 0);
      accB[ci] = __builtin_amdgcn_mfma_f32_16x16x32_f16(zB, B4[ci][ks], accB[ci], 0, 0, 0);
    }
  }

  // biased logits -> LDS, swizzled at 16B granularity.
#pragma unroll
  for (int es = 0; es < 2; ++es) {
    f32x4* ac = es ? accB : accA;
#pragma unroll
    for (int ci = 0; ci < 3; ++ci) {
      int word = ci * 16 + lr;
      int chunk = word >> 2, off = word & 3;
      float bb = b4p[word];
#pragma unroll
      for (int r = 0; r < 4; ++r) {
        int row = w * 32 + es * 16 + lh * 4 + r;
        lg[row * 64 + ((chunk ^ (row & 15)) << 2) + off] = ac[ci][r] + bb;
      }
    }
  }
  __syncthreads();
  if (t >= 128) return;

  // phase 2: one thread per row; 10x ds_read_b128, exp-sum, log, plain stores.
  float v[40];
  float s = 0.f;
#pragma unroll
  for (int c = 0; c < 10; ++c) {
    f32x4 q = *(const f32x4*)&lg[t * 64 + ((c ^ (t & 15)) << 2)];
    v[c * 4 + 0] = q[0]; v[c * 4 + 1] = q[1];
    v[c * 4 + 2] = q[2]; v[c * 4 + 3] = q[3];
  }
#pragma unroll
  for (int i = 0; i < 40; ++i) s += __expf(v[i]);
  float lse = __logf(s);
  float* op = out + ((long)blockIdx.x * 128 + t) * 40;
#pragma unroll
  for (int c = 0; c < 10; ++c) {
    f32x4 o;
    o[0] = v[c * 4 + 0] - lse; o[1] = v[c * 4 + 1] - lse;
    o[2] = v[c * 4 + 2] - lse; o[3] = v[c * 4 + 3] - lse;
    *(f32x4*)(op + c * 4) = o;
  }
}

extern "C" void kernel_launch(void* const* d_in, const int* in_sizes, int n_in,
                              void* d_out, int out_size, void* d_ws, size_t ws_size,
                              hipStream_t stream) {
  const float* x = (const float*)d_in[0];
  const int* ei = (const int*)d_in[1];
  const float* W1 = (const float*)d_in[2];
  const float* b1 = (const float*)d_in[3];
  const float* W2 = (const float*)d_in[4];
  const float* b2 = (const float*)d_in[5];
  const float* W3 = (const float*)d_in[6];
  const float* b3 = (const float*)d_in[7];
  const float* W4 = (const float*)d_in[8];
  const float* b4 = (const float*)d_in[9];
  char* ws = (char*)d_ws;
  int* cnt = (int*)(ws + 0);
  unsigned short* pad = (unsigned short*)(ws + 200064);
  unsigned short* S = (unsigned short*)(ws + 13000192);  // PQ aliases S (dead after agg)
  unsigned short* Ypr = (unsigned short*)(ws + 38600192);
  unsigned short* w1f = (unsigned short*)(ws + 64200192);
  unsigned short* w2f = (unsigned short*)(ws + 64331264);
  unsigned short* w3f = (unsigned short*)(ws + 64396800);
  unsigned short* w4f = (unsigned short*)(ws + 64462336);
  float* b4p = (float*)(ws + 64474624);
  float* out = (float*)d_out;

  (void)hipMemsetAsync(ws, 0, 200064, stream);  // cnt
  k_prep_scatter<<<3662, 256, 0, stream>>>(W1, W2, W3, W4, b4, w1f, w2f, w3f, w4f, b4p,
                                           ei, cnt, pad);
  k_sy<<<782, 512, 0, stream>>>(x, w1f, b1, S, Ypr);
  k_edge_agg<<<6250, 512, 0, stream>>>(S, Ypr, cnt, pad);
  k_pq<<<782, 256, 0, stream>>>(Ypr, S, w2f, b2, w3f, b3);
  k_head<<<6250, 256, 0, stream>>>(S, ei, w4f, b4p, out);
}

// Round 14
// 262.063 us; speedup vs baseline: 1.7880x; 1.0731x over previous
//
#include <hip/hip_runtime.h>
#include <hip/hip_bf16.h>

// Round 14: revert to round-11 exactly (best measured: 265.2 us, absmax 0.03125).
// Full f16 pipeline; packed v_pk_add_f16/v_pk_max_f16 z-construction; 2-chain head;
// LDS-staged contiguous bulk NT output dump.
//   S = x@W1[0:128,:]            -> S   [50000][256] f16
//   Y' = x@W1[128:256,:]+b1      -> Ypr [50000][256] f16 (mean overwrites in-place)
//   bucket: pos=atomicAdd(cnt[d]); pad[d*128+pos]=(ushort)src
//   mean_d = avg_i relu(S[pad[d][i]]+Y'[d])   (wave per node, no LDS/barriers)
//   h = relu(mean@W2+b2); [P|Q'(+b3)] = h@W3cat -> PQ (aliases dead S)
//   z = relu(P[src]+Q'[dst]) (packed f16); logits=z@W4+b4; log_softmax -> LDS -> out
// ws (bytes):
//   cnt  int[50000]            @0          (memset)
//   pad  ushort[50000*128]     @200064     (12.8 MB)
//   S/PQ f16[50000][256]       @13000192
//   Ypr  f16[50000][256]       @38600192
//   w1f @64200192  w2f @64331264  w3f @64396800  w4f @64462336  b4p @64474624
// total ~64.5 MB

typedef _Float16 f16x8 __attribute__((ext_vector_type(8)));
typedef _Float16 f16x4 __attribute__((ext_vector_type(4)));
typedef float f32x4 __attribute__((ext_vector_type(4)));

#define N_NODES 50000
#define N_EDGES 800000

__device__ __forceinline__ unsigned short f2h(float f) {
  _Float16 h = (_Float16)f;  // v_cvt_f16_f32 (RNE)
  return __builtin_bit_cast(unsigned short, h);
}
// int64-vs-int32 edge_index probe (values < 2^31 -> high words zero)
__device__ __forceinline__ int probe64(const int* ei) {
  return (ei[1] == 0 && ei[3] == 0 && ei[5] == 0 && ei[7] == 0) ? 1 : 0;
}
__device__ __forceinline__ int ld_src(const int* ei, int m64, int e) {
  return m64 ? ei[2 * e] : ei[e];
}
__device__ __forceinline__ int ld_dst(const int* ei, int m64, int e) {
  return m64 ? ei[2 * N_EDGES + 2 * e] : ei[N_EDGES + e];
}

// Fused: blocks [0,537) pack weight fragments; blocks [537,3662) count+bucket-scatter.
__global__ void k_prep_scatter(const float* __restrict__ W1, const float* __restrict__ W2,
                               const float* __restrict__ W3, const float* __restrict__ W4,
                               const float* __restrict__ b4,
                               unsigned short* __restrict__ w1f, unsigned short* __restrict__ w2f,
                               unsigned short* __restrict__ w3f, unsigned short* __restrict__ w4f,
                               float* __restrict__ b4p, const int* __restrict__ ei,
                               int* __restrict__ cnt, unsigned short* __restrict__ pad) {
  const int t = threadIdx.x;
  if (blockIdx.x >= 537) {
    int e = (blockIdx.x - 537) * 256 + t;
    int m64 = probe64(ei);
    int s = ld_src(ei, m64, e), d = ld_dst(ei, m64, e);
    int pos = atomicAdd(&cnt[d], 1);
    pad[(d << 7) + pos] = (unsigned short)s;
    return;
  }
  int gid = blockIdx.x * 256 + t;
  if (gid < 65536) {  // w1f: Bcat1[128][512], ct32 ks4
    int i = gid & 7, lane = (gid >> 3) & 63, ks = (gid >> 9) & 3, ct = gid >> 11;
    int k = ks * 32 + (lane >> 4) * 8 + i;
    int c = ct * 16 + (lane & 15);
    float v = (c < 256) ? W1[k * 256 + c] : W1[(128 + k) * 256 + (c - 256)];
    w1f[gid] = f2h(v);
  } else if (gid < 98304) {  // w2f: W2[256][128], ct8 ks8
    int f = gid - 65536;
    int i = f & 7, lane = (f >> 3) & 63, ks = (f >> 9) & 7, ct = f >> 12;
    int k = ks * 32 + (lane >> 4) * 8 + i;
    int c = ct * 16 + (lane & 15);
    w2f[f] = f2h(W2[k * 128 + c]);
  } else if (gid < 131072) {  // w3f: Bcat3[128][256], ct16 ks4
    int f = gid - 98304;
    int i = f & 7, lane = (f >> 3) & 63, ks = (f >> 9) & 3, ct = f >> 11;
    int k = ks * 32 + (lane >> 4) * 8 + i;
    int c = ct * 16 + (lane & 15);
    float v = (c < 128) ? W3[k * 128 + c] : W3[(128 + k) * 128 + (c - 128)];
    w3f[f] = f2h(v);
  } else if (gid < 137216) {  // w4f: W4[128][40->48], ct3 ks4
    int f = gid - 131072;
    int i = f & 7, lane = (f >> 3) & 63, ks = (f >> 9) & 3, ct = f >> 11;
    int k = ks * 32 + (lane >> 4) * 8 + i;
    int c = ct * 16 + (lane & 15);
    w4f[f] = (c < 40) ? f2h(W4[k * 40 + c]) : (unsigned short)0;
  } else if (gid < 137264) {
    int c = gid - 137216;
    b4p[c] = (c < 40) ? b4[c] : 0.f;
  }
}

// SY GEMM: [S|Y'] = x @ [W1top | W1bot], +b1 on Y' cols. 64-row tiles, 8 waves.
__global__ __launch_bounds__(512, 2) void k_sy(const float* __restrict__ x,
                                               const unsigned short* __restrict__ w1f,
                                               const float* __restrict__ b1,
                                               unsigned short* __restrict__ S,
                                               unsigned short* __restrict__ Ypr) {
  __shared__ __attribute__((aligned(16))) short A[64 * 128];  // 16 KB swizzled (256B rows)
  const int t = threadIdx.x;
  const int nb = blockIdx.x * 64;
  const int nv = min(64, N_NODES - nb);
  const int w = t >> 6, l = t & 63, lr = l & 15, lh = l >> 4;

  f16x8 B[4][4];
#pragma unroll
  for (int ci = 0; ci < 4; ++ci)
#pragma unroll
    for (int ks = 0; ks < 4; ++ks)
      B[ci][ks] = *(const f16x8*)(w1f + (((w * 4 + ci) * 4 + ks) * 64 + l) * 8);

#pragma unroll
  for (int j = 0; j < 2; ++j) {
    int c = t + 512 * j;
    int row = c >> 4, ck = c & 15;
    int rr = (row < nv) ? row : 0;
    const float* gp = x + (long)(nb + rr) * 128 + ck * 8;
    float4 v0 = *(const float4*)gp;
    float4 v1 = *(const float4*)(gp + 4);
    f16x8 o;
    o[0] = (_Float16)v0.x; o[1] = (_Float16)v0.y;
    o[2] = (_Float16)v0.z; o[3] = (_Float16)v0.w;
    o[4] = (_Float16)v1.x; o[5] = (_Float16)v1.y;
    o[6] = (_Float16)v1.z; o[7] = (_Float16)v1.w;
    int off = (row << 8) + (ck << 4);
    off ^= (row & 7) << 4;
    *(f16x8*)((char*)A + off) = o;
  }
  __syncthreads();

#pragma unroll
  for (int rt = 0; rt < 4; ++rt) {
    f32x4 acc[4] = {};
#pragma unroll
    for (int ks = 0; ks < 4; ++ks) {
      int row = rt * 16 + lr;
      int off = (row << 8) + (ks << 6) + (lh << 4);
      off ^= (row & 7) << 4;
      f16x8 a = *(const f16x8*)((const char*)A + off);
#pragma unroll
      for (int ci = 0; ci < 4; ++ci)
        acc[ci] = __builtin_amdgcn_mfma_f32_16x16x32_f16(a, B[ci][ks], acc[ci], 0, 0, 0);
    }
#pragma unroll
    for (int ci = 0; ci < 4; ++ci) {
      int col = (w * 4 + ci) * 16 + lr;
#pragma unroll
      for (int r = 0; r < 4; ++r) {
        int row = rt * 16 + lh * 4 + r;
        if (row < nv) {
          if (col < 256) {
            S[(long)(nb + row) * 256 + col] = f2h(acc[ci][r]);
          } else {
            Ypr[(long)(nb + row) * 256 + (col - 256)] = f2h(acc[ci][r] + b1[col - 256]);
          }
        }
      }
    }
  }
}

// Mean of relu(S[s]+Y'[d]) over node d's bucket; one wave per node, lane owns 4 dims.
__global__ __launch_bounds__(512) void k_edge_agg(const unsigned short* __restrict__ S,
                                                  unsigned short* __restrict__ Ypr,
                                                  const int* __restrict__ cnt,
                                                  const unsigned short* __restrict__ pad) {
  const int t = threadIdx.x, w = t >> 6, l = t & 63;
  const int d = blockIdx.x * 8 + w;
  const int n = cnt[d];
  const unsigned short* lp = pad + (d << 7);
  unsigned short* Yp = Ypr + (long)d * 256 + l * 4;
  const f16x4 y = *(const f16x4*)Yp;
  float a0 = 0.f, a1 = 0.f, a2 = 0.f, a3 = 0.f;
  int pos = 0;
  for (; pos + 8 <= n; pos += 8) {
    f16x4 u[8];
#pragma unroll
    for (int j = 0; j < 8; ++j) {
      int s = (int)lp[pos + j];
      u[j] = *(const f16x4*)(S + (long)s * 256 + l * 4);
    }
#pragma unroll
    for (int j = 0; j < 8; ++j) {
      f16x4 z = u[j] + y;                              // v_pk_add_f16 x2
      z = __builtin_elementwise_max(z, f16x4{});       // v_pk_max_f16 x2
      a0 += (float)z[0]; a1 += (float)z[1];
      a2 += (float)z[2]; a3 += (float)z[3];
    }
  }
  for (; pos < n; ++pos) {
    int s = (int)lp[pos];
    f16x4 u = *(const f16x4*)(S + (long)s * 256 + l * 4);
    f16x4 z = u + y;
    z = __builtin_elementwise_max(z, f16x4{});
    a0 += (float)z[0]; a1 += (float)z[1];
    a2 += (float)z[2]; a3 += (float)z[3];
  }
  float inv = 1.0f / fmaxf((float)n, 1.0f);
  f16x4 o;
  o[0] = (_Float16)(a0 * inv); o[1] = (_Float16)(a1 * inv);
  o[2] = (_Float16)(a2 * inv); o[3] = (_Float16)(a3 * inv);
  *(f16x4*)Yp = o;  // mean overwrites Y' (only this wave touches row d)
}

// h = relu(mean@W2+b2); [P|Q'(+b3)] = h@W3cat -> PQ (aliases dead S). 64 nodes/block.
__global__ __launch_bounds__(256, 2) void k_pq(const unsigned short* __restrict__ Ypr,
                                               unsigned short* __restrict__ PQ,
                                               const unsigned short* __restrict__ w2f,
                                               const float* __restrict__ b2,
                                               const unsigned short* __restrict__ w3f,
                                               const float* __restrict__ b3) {
  __shared__ __attribute__((aligned(16))) short M[64 * 256];  // 32 KB (512B rows, swizzled)
  __shared__ __attribute__((aligned(16))) short H[64 * 128];  // 16 KB (256B rows, swizzled)
  const int t = threadIdx.x;
  const int nb = blockIdx.x * 64;
  const int nv = min(64, N_NODES - nb);
  const int w = t >> 6, l = t & 63, lr = l & 15, lh = l >> 4;

  f16x8 B2[2][8];
#pragma unroll
  for (int ci = 0; ci < 2; ++ci)
#pragma unroll
    for (int ks = 0; ks < 8; ++ks)
      B2[ci][ks] = *(const f16x8*)(w2f + (((w * 2 + ci) * 8 + ks) * 64 + l) * 8);

#pragma unroll
  for (int j = 0; j < 8; ++j) {
    int c = t + 256 * j;
    int row = c >> 5, ck = c & 31;
    int rr = (row < nv) ? row : 0;
    int4 v = *(const int4*)(Ypr + (long)(nb + rr) * 256 + ck * 8);
    int off = (row << 9) + (ck << 4);
    off ^= (row & 7) << 4;
    *(int4*)((char*)M + off) = v;
  }
  __syncthreads();

#pragma unroll
  for (int rt = 0; rt < 4; ++rt) {
    f32x4 acc[2] = {};
#pragma unroll
    for (int ks = 0; ks < 8; ++ks) {
      int row = rt * 16 + lr;
      int off = (row << 9) + (ks << 6) + (lh << 4);
      off ^= (row & 7) << 4;
      f16x8 a = *(const f16x8*)((const char*)M + off);
      acc[0] = __builtin_amdgcn_mfma_f32_16x16x32_f16(a, B2[0][ks], acc[0], 0, 0, 0);
      acc[1] = __builtin_amdgcn_mfma_f32_16x16x32_f16(a, B2[1][ks], acc[1], 0, 0, 0);
    }
#pragma unroll
    for (int ci = 0; ci < 2; ++ci) {
      int col = (w * 2 + ci) * 16 + lr;
      float bb = b2[col];
#pragma unroll
      for (int r = 0; r < 4; ++r) {
        int row = rt * 16 + lh * 4 + r;
        int off = (row << 8) + (col << 1);
        off ^= (row & 7) << 4;
        *(short*)((char*)H + off) = (short)f2h(fmaxf(acc[ci][r] + bb, 0.f));
      }
    }
  }
  __syncthreads();

  f16x8 B3[4][4];
#pragma unroll
  for (int ci = 0; ci < 4; ++ci)
#pragma unroll
    for (int ks = 0; ks < 4; ++ks)
      B3[ci][ks] = *(const f16x8*)(w3f + (((w * 4 + ci) * 4 + ks) * 64 + l) * 8);

#pragma unroll
  for (int rt = 0; rt < 4; ++rt) {
    f32x4 acc[4] = {};
#pragma unroll
    for (int ks = 0; ks < 4; ++ks) {
      int row = rt * 16 + lr;
      int off = (row << 8) + (ks << 6) + (lh << 4);
      off ^= (row & 7) << 4;
      f16x8 a = *(const f16x8*)((const char*)H + off);
#pragma unroll
      for (int ci = 0; ci < 4; ++ci)
        acc[ci] = __builtin_amdgcn_mfma_f32_16x16x32_f16(a, B3[ci][ks], acc[ci], 0, 0, 0);
    }
#pragma unroll
    for (int ci = 0; ci < 4; ++ci) {
      int col = (w * 4 + ci) * 16 + lr;
      float bb = (col >= 128) ? b3[col - 128] : 0.f;
#pragma unroll
      for (int r = 0; r < 4; ++r) {
        int row = rt * 16 + lh * 4 + r;
        if (row < nv) PQ[(long)(nb + row) * 256 + col] = f2h(acc[ci][r] + bb);
      }
    }
  }
}

// Head: 32 edges/wave (2 chains); z = relu(P+Q) via packed f16; logits staged in
// LDS, bulk wave-wide contiguous NT float4 dump.
__global__ __launch_bounds__(256) void k_head(const unsigned short* __restrict__ PQ,
                                              const int* __restrict__ ei,
                                              const unsigned short* __restrict__ w4f,
                                              const float* __restrict__ b4p,
                                              float* __restrict__ out) {
  __shared__ __attribute__((aligned(16))) float lg[128 * 40];  // 20480 B
  const int t = threadIdx.x, w = t >> 6, l = t & 63, lr = l & 15, lh = l >> 4;
  const int m64 = probe64(ei);
  const int eb = blockIdx.x * 128 + w * 32;
  const int elA = eb + lr;
  const int elB = eb + 16 + lr;
  const int snA = ld_src(ei, m64, elA), dnA = ld_dst(ei, m64, elA);
  const int snB = ld_src(ei, m64, elB), dnB = ld_dst(ei, m64, elB);
  const unsigned short* PpA = PQ + (long)snA * 256;
  const unsigned short* QpA = PQ + (long)dnA * 256 + 128;
  const unsigned short* PpB = PQ + (long)snB * 256;
  const unsigned short* QpB = PQ + (long)dnB * 256 + 128;

  f16x8 B4[3][4];
#pragma unroll
  for (int ci = 0; ci < 3; ++ci)
#pragma unroll
    for (int ks = 0; ks < 4; ++ks)
      B4[ci][ks] = *(const f16x8*)(w4f + ((ci * 4 + ks) * 64 + l) * 8);

  f32x4 accA[3] = {};
  f32x4 accB[3] = {};
#pragma unroll
  for (int ks = 0; ks < 4; ++ks) {
    f16x8 pA = *(const f16x8*)(PpA + ks * 32 + lh * 8);
    f16x8 qA = *(const f16x8*)(QpA + ks * 32 + lh * 8);
    f16x8 pB = *(const f16x8*)(PpB + ks * 32 + lh * 8);
    f16x8 qB = *(const f16x8*)(QpB + ks * 32 + lh * 8);
    f16x8 zA = pA + qA;                              // 4x v_pk_add_f16
    zA = __builtin_elementwise_max(zA, f16x8{});     // 4x v_pk_max_f16
    f16x8 zB = pB + qB;
    zB = __builtin_elementwise_max(zB, f16x8{});
#pragma unroll
    for (int ci = 0; ci < 3; ++ci) {
      accA[ci] = __builtin_amdgcn_mfma_f32_16x16x32_f16(zA, B4[ci][ks], accA[ci], 0, 0, 0);
      accB[ci] = __builtin_amdgcn_mfma_f32_16x16x32_f16(zB, B4[ci][ks], accB[ci], 0, 0, 0);
    }
  }

  const bool val2 = lr < 8;
  const float bb0 = b4p[lr], bb1 = b4p[16 + lr], bb2 = b4p[32 + lr];
#pragma unroll
  for (int es = 0; es < 2; ++es) {
    float lg0[4], lg1[4], lg2[4];
#pragma unroll
    for (int r = 0; r < 4; ++r) {
      f32x4* ac = es ? accB : accA;
      lg0[r] = ac[0][r] + bb0;
      lg1[r] = ac[1][r] + bb1;
      lg2[r] = ac[2][r] + bb2;
    }
#pragma unroll
    for (int r = 0; r < 4; ++r) {
      float m = fmaxf(lg0[r], lg1[r]);
      if (val2) m = fmaxf(m, lg2[r]);
      m = fmaxf(m, __shfl_xor(m, 1, 64));
      m = fmaxf(m, __shfl_xor(m, 2, 64));
      m = fmaxf(m, __shfl_xor(m, 4, 64));
      m = fmaxf(m, __shfl_xor(m, 8, 64));
      float s = __expf(lg0[r] - m) + __expf(lg1[r] - m) + (val2 ? __expf(lg2[r] - m) : 0.f);
      s += __shfl_xor(s, 1, 64);
      s += __shfl_xor(s, 2, 64);
      s += __shfl_xor(s, 4, 64);
      s += __shfl_xor(s, 8, 64);
      float lse = m + __logf(s);
      int row = w * 32 + es * 16 + lh * 4 + r;
      lg[row * 40 + lr] = lg0[r] - lse;
      lg[row * 40 + 16 + lr] = lg1[r] - lse;
      if (val2) lg[row * 40 + 32 + lr] = lg2[r] - lse;
    }
  }
  __syncthreads();

  // bulk dump: 20480 B = 5 passes x 256 threads x 16 B, contiguous.
  const f32x4* srcv = (const f32x4*)lg;
  f32x4* dstv = (f32x4*)(out + (long)blockIdx.x * 5120);
#pragma unroll
  for (int p = 0; p < 5; ++p) {
    __builtin_nontemporal_store(srcv[t + 256 * p], &dstv[t + 256 * p]);
  }
}

extern "C" void kernel_launch(void* const* d_in, const int* in_sizes, int n_in,
                              void* d_out, int out_size, void* d_ws, size_t ws_size,
                              hipStream_t stream) {
  const float* x = (const float*)d_in[0];
  const int* ei = (const int*)d_in[1];
  const float* W1 = (const float*)d_in[2];
  const float* b1 = (const float*)d_in[3];
  const float* W2 = (const float*)d_in[4];
  const float* b2 = (const float*)d_in[5];
  const float* W3 = (const float*)d_in[6];
  const float* b3 = (const float*)d_in[7];
  const float* W4 = (const float*)d_in[8];
  const float* b4 = (const float*)d_in[9];
  char* ws = (char*)d_ws;
  int* cnt = (int*)(ws + 0);
  unsigned short* pad = (unsigned short*)(ws + 200064);
  unsigned short* S = (unsigned short*)(ws + 13000192);  // PQ aliases S (dead after agg)
  unsigned short* Ypr = (unsigned short*)(ws + 38600192);
  unsigned short* w1f = (unsigned short*)(ws + 64200192);
  unsigned short* w2f = (unsigned short*)(ws + 64331264);
  unsigned short* w3f = (unsigned short*)(ws + 64396800);
  unsigned short* w4f = (unsigned short*)(ws + 64462336);
  float* b4p = (float*)(ws + 64474624);
  float* out = (float*)d_out;

  (void)hipMemsetAsync(ws, 0, 200064, stream);  // cnt
  k_prep_scatter<<<3662, 256, 0, stream>>>(W1, W2, W3, W4, b4, w1f, w2f, w3f, w4f, b4p,
                                           ei, cnt, pad);
  k_sy<<<782, 512, 0, stream>>>(x, w1f, b1, S, Ypr);
  k_edge_agg<<<6250, 512, 0, stream>>>(S, Ypr, cnt, pad);
  k_pq<<<782, 256, 0, stream>>>(Ypr, S, w2f, b2, w3f, b3);
  k_head<<<6250, 256, 0, stream>>>(S, ei, w4f, b4p, out);
}